// Round 1
// baseline (834.107 us; speedup 1.0000x reference)
//
#include <hip/hip_runtime.h>

// CMValidator: per batch (B=262144) of 5 vertices in R^128:
//   - 10 pairwise squared distances (output 0, B x 10)
//   - squared simplex volume via Cayley-Menger det (output 1, B x 1)
// Memory-bound: 640 MB read, 11.5 MB write -> ~103 us floor at 6.3 TB/s.
//
// Layout: 16 lanes per batch (4 batches per wave). Lane sl owns dims
// [4sl,4sl+4) and [64+4sl,64+4sl+4) of each vertex -> each load instruction
// covers 256 B contiguous per 16-lane group (fully coalesced).
// 15 dot-product partials per lane, 4-step shfl_xor butterfly within the
// 16-group, then every lane redundantly computes d2 + det (cheap epilogue).
//
// 6x6 CM det reduced analytically: after eliminating the border rows with
// unit pivots, det(CM) = -det(S) where S is 4x4 with
//   S[ii] = -2*d2[0][i+1],  S[ij] = d2[i+1][j+1] - d2[0][i+1] - d2[0][j+1]
// S = -2 * Gram(edge vectors) -> definite -> direct cofactor det is stable.
// vol2 = PREFACTOR * det(CM) = det(S)/9216.

__global__ __launch_bounds__(256) void cm_kernel(const float* __restrict__ verts,
                                                 float* __restrict__ out,
                                                 int B) {
    int t  = blockIdx.x * blockDim.x + threadIdx.x;
    int b  = t >> 4;
    int sl = t & 15;
    if (b >= B) return;

    const float4* base = (const float4*)(verts + (size_t)b * 640);

    // 5 vertices x 2 half-vectors (8 floats per lane per vertex)
    float4 v[5][2];
#pragma unroll
    for (int i = 0; i < 5; ++i) {
        v[i][0] = base[i * 32 + sl];        // dims [4sl, 4sl+4)
        v[i][1] = base[i * 32 + 16 + sl];   // dims [64+4sl, 64+4sl+4)
    }

    // 15 pair partial dots, (i,j) with i<=j in lexicographic order:
    // idx: (0,0)=0 (0,1)=1 (0,2)=2 (0,3)=3 (0,4)=4 (1,1)=5 (1,2)=6 (1,3)=7
    //      (1,4)=8 (2,2)=9 (2,3)=10 (2,4)=11 (3,3)=12 (3,4)=13 (4,4)=14
    float acc[15];
    {
        int idx = 0;
#pragma unroll
        for (int i = 0; i < 5; ++i) {
#pragma unroll
            for (int j = i; j < 5; ++j) {
                float s;
                s = v[i][0].x * v[j][0].x;
                s = fmaf(v[i][0].y, v[j][0].y, s);
                s = fmaf(v[i][0].z, v[j][0].z, s);
                s = fmaf(v[i][0].w, v[j][0].w, s);
                s = fmaf(v[i][1].x, v[j][1].x, s);
                s = fmaf(v[i][1].y, v[j][1].y, s);
                s = fmaf(v[i][1].z, v[j][1].z, s);
                s = fmaf(v[i][1].w, v[j][1].w, s);
                acc[idx++] = s;
            }
        }
    }

    // Butterfly reduction within the 16-lane group; every lane ends with sums.
#pragma unroll
    for (int m = 1; m < 16; m <<= 1) {
#pragma unroll
        for (int k = 0; k < 15; ++k)
            acc[k] += __shfl_xor(acc[k], m, 64);
    }

    const float n0 = acc[0], n1 = acc[5], n2 = acc[9], n3 = acc[12], n4 = acc[14];

    // relu'd squared distances in combinations(5,2) order
    float p0 = fmaxf(fmaf(-2.0f, acc[1],  n0 + n1), 0.0f);  // d01
    float p1 = fmaxf(fmaf(-2.0f, acc[2],  n0 + n2), 0.0f);  // d02
    float p2 = fmaxf(fmaf(-2.0f, acc[3],  n0 + n3), 0.0f);  // d03
    float p3 = fmaxf(fmaf(-2.0f, acc[4],  n0 + n4), 0.0f);  // d04
    float p4 = fmaxf(fmaf(-2.0f, acc[6],  n1 + n2), 0.0f);  // d12
    float p5 = fmaxf(fmaf(-2.0f, acc[7],  n1 + n3), 0.0f);  // d13
    float p6 = fmaxf(fmaf(-2.0f, acc[8],  n1 + n4), 0.0f);  // d14
    float p7 = fmaxf(fmaf(-2.0f, acc[10], n2 + n3), 0.0f);  // d23
    float p8 = fmaxf(fmaf(-2.0f, acc[11], n2 + n4), 0.0f);  // d24
    float p9 = fmaxf(fmaf(-2.0f, acc[13], n3 + n4), 0.0f);  // d34

    // 4x4 reduced CM matrix S (symmetric)
    const float m00 = -2.0f * p0;
    const float m11 = -2.0f * p1;
    const float m22 = -2.0f * p2;
    const float m33 = -2.0f * p3;
    const float m01 = p4 - p0 - p1;
    const float m02 = p5 - p0 - p2;
    const float m03 = p6 - p0 - p3;
    const float m12 = p7 - p1 - p2;
    const float m13 = p8 - p1 - p3;
    const float m23 = p9 - p2 - p3;

    // det(S) via 2x2-minor expansion (symmetric: m10=m01, etc.)
    const float A = m00 * m11 - m01 * m01;
    const float Bb = m00 * m12 - m02 * m01;
    const float C = m00 * m13 - m03 * m01;
    const float D = m01 * m12 - m02 * m11;
    const float E = m01 * m13 - m03 * m11;
    const float F = m02 * m13 - m03 * m12;
    const float G = m02 * m13 - m12 * m03;  // rows 2,3 cols 0,1
    const float H = m02 * m23 - m22 * m03;
    const float I = m02 * m33 - m23 * m03;
    const float J = m12 * m23 - m22 * m13;
    const float Kk = m12 * m33 - m23 * m13;
    const float L = m22 * m33 - m23 * m23;

    const float detS = A * L - Bb * Kk + C * J + D * I - E * H + F * G;
    const float vol2 = detS * (1.0f / 9216.0f);

    // Output 0: d2_pairs, lanes 0..9 write -> 40 contiguous floats per wave.
    float pv = p0;
    pv = (sl == 1) ? p1 : pv;
    pv = (sl == 2) ? p2 : pv;
    pv = (sl == 3) ? p3 : pv;
    pv = (sl == 4) ? p4 : pv;
    pv = (sl == 5) ? p5 : pv;
    pv = (sl == 6) ? p6 : pv;
    pv = (sl == 7) ? p7 : pv;
    pv = (sl == 8) ? p8 : pv;
    pv = (sl == 9) ? p9 : pv;
    if (sl < 10)
        out[(size_t)b * 10 + sl] = pv;

    // Output 1: vol2 at offset B*10
    if (sl == 10)
        out[(size_t)B * 10 + b] = vol2;
}

extern "C" void kernel_launch(void* const* d_in, const int* in_sizes, int n_in,
                              void* d_out, int out_size, void* d_ws, size_t ws_size,
                              hipStream_t stream) {
    const float* verts = (const float*)d_in[0];
    float* out = (float*)d_out;
    const int B = in_sizes[0] / (5 * 128);

    const int threads = 256;                    // 16 batches per block
    const int blocks = (B * 16 + threads - 1) / threads;
    hipLaunchKernelGGL(cm_kernel, dim3(blocks), dim3(threads), 0, stream,
                       verts, out, B);
}

// Round 2
// 832.961 us; speedup vs baseline: 1.0014x; 1.0014x over previous
//
#include <hip/hip_runtime.h>

// CMValidator: per batch (B=262144) of 5 vertices in R^128:
//   - 10 pairwise squared distances (output 0, B x 10)
//   - squared simplex volume via Cayley-Menger det (output 1, B x 1)
// Memory-bound: 640 MB read, 11.5 MB write -> ~103 us floor at 6.3 TB/s.
//
// Layout: 16 lanes per batch (4 batches per wave). Lane sl owns dims
// [4sl,4sl+4) and [64+4sl,64+4sl+4) of each vertex -> each load instruction
// covers 256 B contiguous per 16-lane group (fully coalesced).
//
// Round-2 change vs round-1: the 15-value __shfl_xor butterfly (60
// ds_bpermute + lgkmcnt stalls per lane) is replaced by a pure-VALU DPP
// row-rotation reduction (row_ror:1/2/4/8) over 10 direct squared-distance
// partials. No LDS-pipe usage at all; diff-then-square is also numerically
// better than norms - 2*gram.
//
// 6x6 CM det reduced analytically: det(CM) = -det(S), S 4x4 symmetric with
//   S[ii] = -2*d2[0][i+1],  S[ij] = d2[i+1][j+1] - d2[0][i+1] - d2[0][j+1]
// S = -2 * Gram(edge vectors) -> definite -> direct cofactor det is stable.
// vol2 = PREFACTOR * det(CM) = det(S)/9216.  (verified passing in round 1)

template <int CTRL>
__device__ __forceinline__ float row_rotadd(float x) {
    int r = __builtin_amdgcn_update_dpp(0, __builtin_bit_cast(int, x),
                                        CTRL, 0xF, 0xF, false);
    return x + __builtin_bit_cast(float, r);
}

// Full 16-lane (DPP row) sum; every lane of the row ends with the total.
__device__ __forceinline__ float row_reduce16(float x) {
    x = row_rotadd<0x121>(x);  // row_ror:1
    x = row_rotadd<0x122>(x);  // row_ror:2
    x = row_rotadd<0x124>(x);  // row_ror:4
    x = row_rotadd<0x128>(x);  // row_ror:8
    return x;
}

__global__ __launch_bounds__(256) void cm_kernel(const float* __restrict__ verts,
                                                 float* __restrict__ out,
                                                 int B) {
    int t  = blockIdx.x * blockDim.x + threadIdx.x;
    int b  = t >> 4;
    int sl = t & 15;
    if (b >= B) return;

    const float4* base = (const float4*)(verts + (size_t)b * 640);

    // 5 vertices x 2 half-vectors (8 floats per lane per vertex)
    float4 v[5][2];
#pragma unroll
    for (int i = 0; i < 5; ++i) {
        v[i][0] = base[i * 32 + sl];        // dims [4sl, 4sl+4)
        v[i][1] = base[i * 32 + 16 + sl];   // dims [64+4sl, 64+4sl+4)
    }

    // 10 pairwise squared-distance partials, combinations(5,2) order:
    // (0,1)(0,2)(0,3)(0,4)(1,2)(1,3)(1,4)(2,3)(2,4)(3,4)
    float acc[10];
    {
        int idx = 0;
#pragma unroll
        for (int i = 0; i < 5; ++i) {
#pragma unroll
            for (int j = i + 1; j < 5; ++j) {
                float d, s;
                d = v[i][0].x - v[j][0].x; s = d * d;
                d = v[i][0].y - v[j][0].y; s = fmaf(d, d, s);
                d = v[i][0].z - v[j][0].z; s = fmaf(d, d, s);
                d = v[i][0].w - v[j][0].w; s = fmaf(d, d, s);
                d = v[i][1].x - v[j][1].x; s = fmaf(d, d, s);
                d = v[i][1].y - v[j][1].y; s = fmaf(d, d, s);
                d = v[i][1].z - v[j][1].z; s = fmaf(d, d, s);
                d = v[i][1].w - v[j][1].w; s = fmaf(d, d, s);
                acc[idx++] = s;
            }
        }
    }

    // Pure-VALU 16-lane reduction (no LDS pipe, no lgkmcnt stalls).
    float p0 = row_reduce16(acc[0]);
    float p1 = row_reduce16(acc[1]);
    float p2 = row_reduce16(acc[2]);
    float p3 = row_reduce16(acc[3]);
    float p4 = row_reduce16(acc[4]);
    float p5 = row_reduce16(acc[5]);
    float p6 = row_reduce16(acc[6]);
    float p7 = row_reduce16(acc[7]);
    float p8 = row_reduce16(acc[8]);
    float p9 = row_reduce16(acc[9]);

    // 4x4 reduced CM matrix S (symmetric)
    const float m00 = -2.0f * p0;
    const float m11 = -2.0f * p1;
    const float m22 = -2.0f * p2;
    const float m33 = -2.0f * p3;
    const float m01 = p4 - p0 - p1;
    const float m02 = p5 - p0 - p2;
    const float m03 = p6 - p0 - p3;
    const float m12 = p7 - p1 - p2;
    const float m13 = p8 - p1 - p3;
    const float m23 = p9 - p2 - p3;

    // det(S) via 2x2-minor expansion (symmetric: m10=m01, etc.)
    const float A  = m00 * m11 - m01 * m01;
    const float Bb = m00 * m12 - m02 * m01;
    const float C  = m00 * m13 - m03 * m01;
    const float D  = m01 * m12 - m02 * m11;
    const float E  = m01 * m13 - m03 * m11;
    const float F  = m02 * m13 - m03 * m12;
    const float G  = m02 * m13 - m12 * m03;  // rows 2,3 cols 0,1
    const float H  = m02 * m23 - m22 * m03;
    const float I  = m02 * m33 - m23 * m03;
    const float J  = m12 * m23 - m22 * m13;
    const float Kk = m12 * m33 - m23 * m13;
    const float L  = m22 * m33 - m23 * m23;

    const float detS = A * L - Bb * Kk + C * J + D * I - E * H + F * G;
    const float vol2 = detS * (1.0f / 9216.0f);

    // Output 0: d2_pairs, lanes 0..9 write -> 40 contiguous floats per wave.
    float pv = p0;
    pv = (sl == 1) ? p1 : pv;
    pv = (sl == 2) ? p2 : pv;
    pv = (sl == 3) ? p3 : pv;
    pv = (sl == 4) ? p4 : pv;
    pv = (sl == 5) ? p5 : pv;
    pv = (sl == 6) ? p6 : pv;
    pv = (sl == 7) ? p7 : pv;
    pv = (sl == 8) ? p8 : pv;
    pv = (sl == 9) ? p9 : pv;
    if (sl < 10)
        out[(size_t)b * 10 + sl] = fmaxf(pv, 0.0f);

    // Output 1: vol2 at offset B*10
    if (sl == 10)
        out[(size_t)B * 10 + b] = vol2;
}

extern "C" void kernel_launch(void* const* d_in, const int* in_sizes, int n_in,
                              void* d_out, int out_size, void* d_ws, size_t ws_size,
                              hipStream_t stream) {
    const float* verts = (const float*)d_in[0];
    float* out = (float*)d_out;
    const int B = in_sizes[0] / (5 * 128);

    const int threads = 256;                    // 16 batches per block
    const int blocks = (B * 16 + threads - 1) / threads;
    hipLaunchKernelGGL(cm_kernel, dim3(blocks), dim3(threads), 0, stream,
                       verts, out, B);
}